// Round 1
// baseline (106.488 us; speedup 1.0000x reference)
//
#include <hip/hip_runtime.h>
#include <math.h>

#define NPRED 16384
#define NGT   32768
#define BETA  0.45f
#define GAMMA 0.45f

#define BLOCK 256
#define PPT   4                         // preds per thread
#define PRED_PER_BLOCK (BLOCK * PPT)    // 1024
#define GT_TILE 1024
#define PRED_CHUNKS (NPRED / PRED_PER_BLOCK)  // 16
#define GT_SLICES   (NGT / GT_TILE)           // 32

// ---------------------------------------------------------------------------
// Kernel 1: brute-force NN argmin over a gt slice, merged via u64 atomicMin.
// Key = sortable-float(d) << 32 | gt_index  (ties -> lowest index, matching
// jnp.argmin first-occurrence).  d = g^2 - 2*dot(p,g): dropping the per-pred
// constant p^2 does not change the argmin.
// ---------------------------------------------------------------------------
__global__ __launch_bounds__(BLOCK) void nn_kernel(
    const float* __restrict__ pred_feat,
    const float* __restrict__ gt_data,
    unsigned long long* __restrict__ packed)
{
    __shared__ float4 gs[GT_TILE];

    const int chunk = blockIdx.x;
    const int slice = blockIdx.y;
    const int t     = threadIdx.x;
    const int gt_base = slice * GT_TILE;

    // Stage gt slice into LDS as (x, y, z, |g|^2)
    for (int j = t; j < GT_TILE; j += BLOCK) {
        const int gj = gt_base + j;
        const float x = gt_data[gj * 6 + 0];
        const float y = gt_data[gj * 6 + 1];
        const float z = gt_data[gj * 6 + 2];
        gs[j] = make_float4(x, y, z, fmaf(x, x, fmaf(y, y, z * z)));
    }
    __syncthreads();

    float px[PPT], py[PPT], pz[PPT];
    float dmin[PPT];
    int   jmin[PPT];

    const int pred_base = chunk * PRED_PER_BLOCK + t;
#pragma unroll
    for (int p = 0; p < PPT; ++p) {
        const int i = pred_base + p * BLOCK;
        px[p] = pred_feat[i * 6 + 0];
        py[p] = pred_feat[i * 6 + 1];
        pz[p] = pred_feat[i * 6 + 2];
        dmin[p] = INFINITY;
        jmin[p] = 0;
    }

#pragma unroll 4
    for (int j = 0; j < GT_TILE; ++j) {
        const float4 g = gs[j];   // broadcast read: all lanes same addr, no conflict
#pragma unroll
        for (int p = 0; p < PPT; ++p) {
            const float dot = fmaf(px[p], g.x, fmaf(py[p], g.y, pz[p] * g.z));
            const float d   = fmaf(-2.0f, dot, g.w);
            const bool lt = d < dmin[p];
            dmin[p] = lt ? d : dmin[p];
            jmin[p] = lt ? j : jmin[p];
        }
    }

#pragma unroll
    for (int p = 0; p < PPT; ++p) {
        const int i = pred_base + p * BLOCK;
        const unsigned int bits = __float_as_uint(dmin[p]);
        // monotone float->uint transform (handles negative d from rounding)
        const unsigned int key = (bits & 0x80000000u) ? ~bits : (bits | 0x80000000u);
        const unsigned long long pk =
            ((unsigned long long)key << 32) | (unsigned int)(gt_base + jmin[p]);
        atomicMin(&packed[i], pk);
    }
}

// ---------------------------------------------------------------------------
// Kernel 2: gather normals at argmin, mean(1 - cos), plus regularizer term.
// ---------------------------------------------------------------------------
__global__ __launch_bounds__(BLOCK) void finalize_kernel(
    const float* __restrict__ pred_feat,
    const float* __restrict__ gt_data,
    const float* __restrict__ Rm,
    const float* __restrict__ tv,
    const float* __restrict__ sv,
    const unsigned long long* __restrict__ packed,
    float* __restrict__ out)
{
    const int i = blockIdx.x * BLOCK + threadIdx.x;
    float c = 0.0f;
    if (i < NPRED) {
        const unsigned long long pk = packed[i];
        const int idx = (int)(pk & 0xFFFFFFFFull);
        const float nx = pred_feat[i * 6 + 3];
        const float ny = pred_feat[i * 6 + 4];
        const float nz = pred_feat[i * 6 + 5];
        const float gx = gt_data[idx * 6 + 3];
        const float gy = gt_data[idx * 6 + 4];
        const float gz = gt_data[idx * 6 + 5];
        const float pn = fmaxf(sqrtf(fmaf(nx, nx, fmaf(ny, ny, nz * nz))), 1e-12f);
        const float gn = fmaxf(sqrtf(fmaf(gx, gx, fmaf(gy, gy, gz * gz))), 1e-12f);
        const float cosv = fmaf(nx, gx, fmaf(ny, gy, nz * gz)) / (pn * gn);
        c = 1.0f - cosv;
    }
    // wave-64 reduce
#pragma unroll
    for (int off = 32; off > 0; off >>= 1) c += __shfl_down(c, off, 64);
    if ((threadIdx.x & 63) == 0) atomicAdd(out, c * (GAMMA / (float)NPRED));

    if (blockIdx.x == 0 && threadIdx.x == 0) {
        float rs = 0.0f;
#pragma unroll
        for (int k = 0; k < 9; ++k) {
            const float v = Rm[k] - ((k % 4 == 0) ? 1.0f : 0.0f);
            rs = fmaf(v, v, rs);
        }
        const float rot = sqrtf(rs);
        const float tr  = sqrtf(fmaf(tv[0], tv[0], fmaf(tv[1], tv[1], tv[2] * tv[2])));
        const float sc  = (sv[0] - 1.0f) * (sv[0] - 1.0f);
        atomicAdd(out, BETA * (rot + tr + sc));
    }
}

extern "C" void kernel_launch(void* const* d_in, const int* in_sizes, int n_in,
                              void* d_out, int out_size, void* d_ws, size_t ws_size,
                              hipStream_t stream)
{
    const float* pred = (const float*)d_in[0];
    const float* gt   = (const float*)d_in[1];
    const float* Rm   = (const float*)d_in[2];
    const float* tv   = (const float*)d_in[3];
    const float* sv   = (const float*)d_in[4];
    float* out = (float*)d_out;
    unsigned long long* packed = (unsigned long long*)d_ws;

    hipMemsetAsync(packed, 0xFF, NPRED * sizeof(unsigned long long), stream);
    hipMemsetAsync(out, 0, sizeof(float), stream);

    dim3 grid(PRED_CHUNKS, GT_SLICES);
    nn_kernel<<<grid, BLOCK, 0, stream>>>(pred, gt, packed);
    finalize_kernel<<<NPRED / BLOCK, BLOCK, 0, stream>>>(pred, gt, Rm, tv, sv, packed, out);
}

// Round 2
// 93.529 us; speedup vs baseline: 1.1386x; 1.1386x over previous
//
#include <hip/hip_runtime.h>
#include <math.h>

#define NPRED 16384
#define NGT   32768
#define BETA  0.45f
#define GAMMA 0.45f

#define BLOCK 256
#define PPT   8                         // preds per thread
#define PRED_PER_BLOCK (BLOCK * PPT)    // 2048
#define GT_TILE 512
#define PRED_CHUNKS (NPRED / PRED_PER_BLOCK)  // 8
#define GT_SLICES   (NGT / GT_TILE)           // 64

// ---------------------------------------------------------------------------
// Kernel 1: brute-force NN argmin over a gt slice, merged via u64 atomicMin.
// LDS holds h = (-2gx, -2gy, -2gz, |g|^2) so that
//   d = g^2 - 2*dot(p,g) = fmaf(px,hx, fmaf(py,hy, fmaf(pz,hz, hw)))
// (dropping the per-pred constant p^2 does not change the argmin).
// 6 VALU ops per pair: 3 fma + cmp + 2 cndmask.
// ---------------------------------------------------------------------------
__global__ __launch_bounds__(BLOCK) void nn_kernel(
    const float* __restrict__ pred_feat,
    const float* __restrict__ gt_data,
    unsigned long long* __restrict__ packed)
{
    __shared__ float4 hs[GT_TILE];

    const int chunk = blockIdx.x;
    const int slice = blockIdx.y;
    const int t     = threadIdx.x;
    const int gt_base = slice * GT_TILE;

    // Stage gt slice into LDS preformatted as (-2x, -2y, -2z, |g|^2)
    for (int j = t; j < GT_TILE; j += BLOCK) {
        const int gj = gt_base + j;
        const float x = gt_data[gj * 6 + 0];
        const float y = gt_data[gj * 6 + 1];
        const float z = gt_data[gj * 6 + 2];
        hs[j] = make_float4(-2.0f * x, -2.0f * y, -2.0f * z,
                            fmaf(x, x, fmaf(y, y, z * z)));
    }
    __syncthreads();

    float px[PPT], py[PPT], pz[PPT];
    float dmin[PPT];
    int   jmin[PPT];

    const int pred_base = chunk * PRED_PER_BLOCK + t;
#pragma unroll
    for (int p = 0; p < PPT; ++p) {
        const int i = pred_base + p * BLOCK;
        px[p] = pred_feat[i * 6 + 0];
        py[p] = pred_feat[i * 6 + 1];
        pz[p] = pred_feat[i * 6 + 2];
        dmin[p] = INFINITY;
        jmin[p] = 0;
    }

#pragma unroll 4
    for (int j = 0; j < GT_TILE; ++j) {
        const float4 h = hs[j];   // broadcast read: all lanes same addr, no conflict
#pragma unroll
        for (int p = 0; p < PPT; ++p) {
            const float d = fmaf(px[p], h.x, fmaf(py[p], h.y, fmaf(pz[p], h.z, h.w)));
            const bool lt = d < dmin[p];
            dmin[p] = lt ? d : dmin[p];
            jmin[p] = lt ? j : jmin[p];
        }
    }

#pragma unroll
    for (int p = 0; p < PPT; ++p) {
        const int i = pred_base + p * BLOCK;
        const unsigned int bits = __float_as_uint(dmin[p]);
        // monotone float->uint transform (d can be negative: g^2-2dot)
        const unsigned int key = (bits & 0x80000000u) ? ~bits : (bits | 0x80000000u);
        const unsigned long long pk =
            ((unsigned long long)key << 32) | (unsigned int)(gt_base + jmin[p]);
        atomicMin(&packed[i], pk);
    }
}

// ---------------------------------------------------------------------------
// Kernel 2: gather normals at argmin, mean(1 - cos), plus regularizer term.
// ---------------------------------------------------------------------------
__global__ __launch_bounds__(BLOCK) void finalize_kernel(
    const float* __restrict__ pred_feat,
    const float* __restrict__ gt_data,
    const float* __restrict__ Rm,
    const float* __restrict__ tv,
    const float* __restrict__ sv,
    const unsigned long long* __restrict__ packed,
    float* __restrict__ out)
{
    const int i = blockIdx.x * BLOCK + threadIdx.x;
    float c = 0.0f;
    if (i < NPRED) {
        const unsigned long long pk = packed[i];
        const int idx = (int)(pk & 0xFFFFFFFFull);
        const float nx = pred_feat[i * 6 + 3];
        const float ny = pred_feat[i * 6 + 4];
        const float nz = pred_feat[i * 6 + 5];
        const float gx = gt_data[idx * 6 + 3];
        const float gy = gt_data[idx * 6 + 4];
        const float gz = gt_data[idx * 6 + 5];
        const float pn = fmaxf(sqrtf(fmaf(nx, nx, fmaf(ny, ny, nz * nz))), 1e-12f);
        const float gn = fmaxf(sqrtf(fmaf(gx, gx, fmaf(gy, gy, gz * gz))), 1e-12f);
        const float cosv = fmaf(nx, gx, fmaf(ny, gy, nz * gz)) / (pn * gn);
        c = 1.0f - cosv;
    }
    // wave-64 reduce
#pragma unroll
    for (int off = 32; off > 0; off >>= 1) c += __shfl_down(c, off, 64);
    if ((threadIdx.x & 63) == 0) atomicAdd(out, c * (GAMMA / (float)NPRED));

    if (blockIdx.x == 0 && threadIdx.x == 0) {
        float rs = 0.0f;
#pragma unroll
        for (int k = 0; k < 9; ++k) {
            const float v = Rm[k] - ((k % 4 == 0) ? 1.0f : 0.0f);
            rs = fmaf(v, v, rs);
        }
        const float rot = sqrtf(rs);
        const float tr  = sqrtf(fmaf(tv[0], tv[0], fmaf(tv[1], tv[1], tv[2] * tv[2])));
        const float sc  = (sv[0] - 1.0f) * (sv[0] - 1.0f);
        atomicAdd(out, BETA * (rot + tr + sc));
    }
}

extern "C" void kernel_launch(void* const* d_in, const int* in_sizes, int n_in,
                              void* d_out, int out_size, void* d_ws, size_t ws_size,
                              hipStream_t stream)
{
    const float* pred = (const float*)d_in[0];
    const float* gt   = (const float*)d_in[1];
    const float* Rm   = (const float*)d_in[2];
    const float* tv   = (const float*)d_in[3];
    const float* sv   = (const float*)d_in[4];
    float* out = (float*)d_out;
    unsigned long long* packed = (unsigned long long*)d_ws;

    hipMemsetAsync(packed, 0xFF, NPRED * sizeof(unsigned long long), stream);
    hipMemsetAsync(out, 0, sizeof(float), stream);

    dim3 grid(PRED_CHUNKS, GT_SLICES);
    nn_kernel<<<grid, BLOCK, 0, stream>>>(pred, gt, packed);
    finalize_kernel<<<NPRED / BLOCK, BLOCK, 0, stream>>>(pred, gt, Rm, tv, sv, packed, out);
}